// Round 4
// baseline (505.043 us; speedup 1.0000x reference)
//
#include <hip/hip_runtime.h>

#define B_SZ 32
#define H_SZ 64
#define W_SZ 64
#define DIM 64
#define K_CODES 512
#define N_VEC (B_SZ * H_SZ * W_SZ)   // 131072
#define Q_OFF 1
#define PERP_OFF 8388609
#define ENC_OFF 8388610

// ---------------------------------------------------------------------------
// Kernel 0: ||e||^2 per code (512 values).
// ---------------------------------------------------------------------------
__global__ __launch_bounds__(64) void ee_kernel(const float* __restrict__ emb_w,
                                                float* __restrict__ ee)
{
    const int k = blockIdx.x * 64 + threadIdx.x;
    const float4* e4 = reinterpret_cast<const float4*>(emb_w + (size_t)k * DIM);
    float s0 = 0, s1 = 0, s2 = 0, s3 = 0;
#pragma unroll
    for (int d4 = 0; d4 < 16; ++d4) {
        const float4 v = e4[d4];
        s0 = fmaf(v.x, v.x, s0); s1 = fmaf(v.y, v.y, s1);
        s2 = fmaf(v.z, v.z, s2); s3 = fmaf(v.w, v.w, s3);
    }
    ee[k] = (s0 + s1) + (s2 + s3);
}

// ---------------------------------------------------------------------------
// Kernel 1: argmin via SGPR-streamed codebook. NO LDS.
//
// Thread = 1 input vector (x in 64 VGPRs). e[k] address is wave-uniform ->
// s_load (K$/L2), FMA takes the SGPR operand directly. 2-code unroll = 8
// independent FMA chains. One-hot zero-fill spread through the k-loop as
// coalesced wave stores (wave zeroes its own 64 rows); after a vmcnt-draining
// __syncthreads, owner threads store the 1.0s (same wave wrote the zeros, so
// barrier fully orders them). dw: wave-cooperative contiguous row atomics,
// x reloaded coalesced from global (L2-hot).
// Tie rule: ascending-k scan, strict <  == numpy argmin (first minimum).
// ---------------------------------------------------------------------------
__global__ __launch_bounds__(256) void argmin_sgpr_kernel(
    const float* __restrict__ inputs,
    const float* __restrict__ emb_w,
    const float* __restrict__ eeg,
    int* __restrict__ idx,
    float* __restrict__ counts,
    float* __restrict__ dw,
    float* __restrict__ enc)
{
    const int t = threadIdx.x;
    const int lane = t & 63;
    const size_t vec = (size_t)blockIdx.x * 256 + t;
    const size_t waveBase = vec - lane;   // first vector owned by this wave

    // ---- x -> registers, ||x||^2 ----
    const float4* xp = reinterpret_cast<const float4*>(inputs + vec * DIM);
    float4 x[16];
    float q0 = 0, q1 = 0, q2 = 0, q3 = 0;
#pragma unroll
    for (int d4 = 0; d4 < 16; ++d4) {
        x[d4] = xp[d4];
        q0 = fmaf(x[d4].x, x[d4].x, q0);
        q1 = fmaf(x[d4].y, x[d4].y, q1);
        q2 = fmaf(x[d4].z, x[d4].z, q2);
        q3 = fmaf(x[d4].w, x[d4].w, q3);
    }
    const float xx = (q0 + q1) + (q2 + q3);

    float best = 3.4e38f;
    int bestk = 0;
    float* encW = enc + waveBase * K_CODES;

    for (int k2 = 0; k2 < K_CODES / 2; ++k2) {
        const int ka = 2 * k2, kb = 2 * k2 + 1;
        const float4* ea = reinterpret_cast<const float4*>(emb_w + (size_t)ka * DIM);
        const float4* eb = reinterpret_cast<const float4*>(emb_w + (size_t)kb * DIM);
        float a0 = 0, a1 = 0, a2 = 0, a3 = 0;
        float b0 = 0, b1 = 0, b2 = 0, b3 = 0;
#pragma unroll
        for (int d4 = 0; d4 < 16; ++d4) {
            const float4 xa = x[d4];
            const float4 va = ea[d4];            // uniform -> s_load_dwordx4
            a0 = fmaf(xa.x, va.x, a0);
            a1 = fmaf(xa.y, va.y, a1);
            a2 = fmaf(xa.z, va.z, a2);
            a3 = fmaf(xa.w, va.w, a3);
            const float4 vb = eb[d4];            // uniform -> s_load_dwordx4
            b0 = fmaf(xa.x, vb.x, b0);
            b1 = fmaf(xa.y, vb.y, b1);
            b2 = fmaf(xa.z, vb.z, b2);
            b3 = fmaf(xa.w, vb.w, b3);
        }
        const float dota = (a0 + a1) + (a2 + a3);
        const float dotb = (b0 + b1) + (b2 + b3);
        const float da = (xx - 2.f * dota) + eeg[ka];
        const float db = (xx - 2.f * dotb) + eeg[kb];
        if (da < best) { best = da; bestk = ka; }
        if (db < best) { best = db; bestk = kb; }

        // ---- spread one-hot zero-fill: 1 coalesced 512B wave-store / 2 codes
        // (wave zeroes its own 64 rows of 512 f32 across the 256 iterations)
        {
            const int row  = k2 >> 2;            // 0..63
            const int part = k2 & 3;             // 0..3 quarters of the row
            *reinterpret_cast<float2*>(
                encW + (size_t)row * K_CODES + part * 128 + lane * 2)
                = make_float2(0.f, 0.f);
        }
    }

    __syncthreads();   // vmcnt(0) drain: zero-fill committed before 1.0 stores

    idx[vec] = bestk;
    atomicAdd(&counts[bestk], 1.0f);
    enc[vec * K_CODES + bestk] = 1.0f;

    // ---- dw segment-sum: wave-cooperative, one contiguous 256B row / instr
    for (int j = 0; j < 64; ++j) {
        const int bkj = __shfl(bestk, j, 64);
        const float xv = inputs[(waveBase + j) * DIM + lane];  // coalesced, L2-hot
        atomicAdd(&dw[(size_t)bkj * DIM + lane], xv);
    }
}

// ---------------------------------------------------------------------------
// Kernel 2: EMA cluster-size + Laplace smoothing + codebook update +
// perplexity. One block of K=512 threads.
// ---------------------------------------------------------------------------
__global__ __launch_bounds__(512) void ema_update_kernel(
    const float* __restrict__ counts,
    const float* __restrict__ ema_cs,
    const float* __restrict__ ema_w,
    const float* __restrict__ dw,
    float* __restrict__ new_emb,
    float* __restrict__ perp_out)
{
    __shared__ float red[K_CODES];
    const int k = threadIdx.x;

    const float cnt = counts[k];
    float cs = ema_cs[k] * 0.99f + 0.01f * cnt;

    red[k] = cs;
    __syncthreads();
    for (int s = K_CODES / 2; s > 0; s >>= 1) {
        if (k < s) red[k] += red[k + s];
        __syncthreads();
    }
    const float n = red[0];
    __syncthreads();

    cs = (cs + 1e-5f) / (n + (float)K_CODES * 1e-5f) * n;

    for (int d = 0; d < DIM; ++d) {
        const float v = ema_w[k * DIM + d] * 0.99f + 0.01f * dw[k * DIM + d];
        new_emb[k * DIM + d] = v / cs;
    }

    const float p = cnt * (1.0f / (float)N_VEC);
    red[k] = p * logf(p + 1e-10f);
    __syncthreads();
    for (int s = K_CODES / 2; s > 0; s >>= 1) {
        if (k < s) red[k] += red[k + s];
        __syncthreads();
    }
    if (k == 0) perp_out[0] = expf(-red[0]);
}

// ---------------------------------------------------------------------------
// Kernel 3: gather quantized = new_emb[idx], straight-through qst,
// NHWC -> NCHW via LDS tile, commitment-loss partials.
// ---------------------------------------------------------------------------
__global__ __launch_bounds__(256) void quantize_kernel(
    const float* __restrict__ inputs,
    const int* __restrict__ idx,
    const float* __restrict__ new_emb,
    float* __restrict__ out_q,
    float* __restrict__ loss_accum)
{
    __shared__ int sIdx[W_SZ];
    __shared__ float tile[DIM][W_SZ + 1];
    __shared__ float wsum[4];

    const int bh = blockIdx.x;
    const int b = bh >> 6, h = bh & 63;
    const int t = threadIdx.x;

    if (t < W_SZ) sIdx[t] = idx[bh * W_SZ + t];
    __syncthreads();

    const float* inRow = inputs + (size_t)bh * W_SZ * DIM;
    const int d = t & 63;
    const int wg = t >> 6;
    float lsum = 0.f;
#pragma unroll
    for (int p = 0; p < 16; ++p) {
        const int w = wg * 16 + p;
        const float xv = inRow[w * DIM + d];
        const float qv = new_emb[sIdx[w] * DIM + d];
        const float diff = qv - xv;
        tile[d][w] = xv + diff;
        lsum = fmaf(diff, diff, lsum);
    }
    __syncthreads();

    const int w2 = t & 63;
    const int dg = t >> 6;
#pragma unroll
    for (int p = 0; p < 16; ++p) {
        const int d2 = dg * 16 + p;
        out_q[(((size_t)b * DIM + d2) * H_SZ + h) * W_SZ + w2] = tile[d2][w2];
    }

    for (int off = 32; off > 0; off >>= 1) lsum += __shfl_down(lsum, off);
    if ((t & 63) == 0) wsum[t >> 6] = lsum;
    __syncthreads();
    if (t == 0) atomicAdd(loss_accum, (wsum[0] + wsum[1]) + (wsum[2] + wsum[3]));
}

__global__ void finalize_kernel(const float* __restrict__ loss_accum,
                                float* __restrict__ out_loss)
{
    out_loss[0] = 0.25f * (loss_accum[0] / 8388608.0f);
}

// ---------------------------------------------------------------------------
extern "C" void kernel_launch(void* const* d_in, const int* in_sizes, int n_in,
                              void* d_out, int out_size, void* d_ws, size_t ws_size,
                              hipStream_t stream)
{
    const float* inputs = (const float*)d_in[0];
    const float* emb_w  = (const float*)d_in[1];
    const float* ema_cs = (const float*)d_in[2];
    const float* ema_w  = (const float*)d_in[3];
    float* out = (float*)d_out;
    float* ws  = (float*)d_ws;

    // ws layout (f32 offsets):
    int*   idxbuf = (int*)ws;            // [0, 131072)
    float* counts = ws + 131072;         // [131072, 131584)
    float* dwbuf  = ws + 131584;         // [131584, 164352)
    float* lossac = ws + 164352;         // [164352]
    float* nemb   = ws + 164353;         // [164353, 197121)
    float* eebuf  = nemb;                // overlay: ee consumed before ema writes

    // one contiguous zero of counts|dw|lossac (133 KB)
    hipMemsetAsync(counts, 0, (512 + 512 * DIM + 1) * sizeof(float), stream);

    ee_kernel<<<K_CODES / 64, 64, 0, stream>>>(emb_w, eebuf);

    argmin_sgpr_kernel<<<N_VEC / 256, 256, 0, stream>>>(
        inputs, emb_w, eebuf, idxbuf, counts, dwbuf, out + ENC_OFF);

    ema_update_kernel<<<1, K_CODES, 0, stream>>>(
        counts, ema_cs, ema_w, dwbuf, nemb, out + PERP_OFF);

    quantize_kernel<<<B_SZ * H_SZ, 256, 0, stream>>>(
        inputs, idxbuf, nemb, out + Q_OFF, lossac);

    finalize_kernel<<<1, 1, 0, stream>>>(lossac, out);
}

// Round 5
// 320.843 us; speedup vs baseline: 1.5741x; 1.5741x over previous
//
#include <hip/hip_runtime.h>

#define DIM 64
#define K_CODES 512
#define N_VEC 131072
#define Q_OFF 1
#define PERP_OFF 8388609
#define ENC_OFF 8388610

using bfrag = __attribute__((ext_vector_type(8))) short;  // 8 bf16 = 4 VGPR
using ffrag = __attribute__((ext_vector_type(4))) float;  // 4 f32 acc

// Exact 3-way bf16 truncation split: x == x0 + x1 + x2 (24 = 8+8+8 mantissa
// bits; each subtraction is exact by the Sterbenz/bit-clearing argument).
__device__ __forceinline__ void split3(float x, short& h0, short& h1, short& h2)
{
    unsigned u0 = __float_as_uint(x);
    h0 = (short)(u0 >> 16);
    float r = x - __uint_as_float(u0 & 0xFFFF0000u);     // exact
    unsigned u1 = __float_as_uint(r);
    h1 = (short)(u1 >> 16);
    float r2 = r - __uint_as_float(u1 & 0xFFFF0000u);    // exact
    h2 = (short)(__float_as_uint(r2) >> 16);             // r2 fits bf16 exactly
}

// ---------------------------------------------------------------------------
// Kernel 0a: ||e||^2 per code.
// ---------------------------------------------------------------------------
__global__ __launch_bounds__(64) void ee_kernel(const float* __restrict__ emb_w,
                                                float* __restrict__ ee)
{
    const int k = blockIdx.x * 64 + threadIdx.x;
    const float4* e4 = reinterpret_cast<const float4*>(emb_w + (size_t)k * DIM);
    float s0 = 0, s1 = 0, s2 = 0, s3 = 0;
#pragma unroll
    for (int d4 = 0; d4 < 16; ++d4) {
        const float4 v = e4[d4];
        s0 = fmaf(v.x, v.x, s0); s1 = fmaf(v.y, v.y, s1);
        s2 = fmaf(v.z, v.z, s2); s3 = fmaf(v.w, v.w, s3);
    }
    ee[k] = (s0 + s1) + (s2 + s3);
}

// ---------------------------------------------------------------------------
// Kernel 0b: pre-split + pre-pack codebook into per-lane MFMA B-fragments.
// epack[((ct*2+db)*3 + s)*64 + lane] = 8 bf16 of split s for
//   code c = ct*16 + (lane&15), d = db*32 + (lane>>4)*8 + 0..7.
// 4096 threads; output 192 KB (stays L2-hot for the main kernel).
// ---------------------------------------------------------------------------
__global__ __launch_bounds__(256) void epack_kernel(const float* __restrict__ emb_w,
                                                    bfrag* __restrict__ epack)
{
    const int t = blockIdx.x * 256 + threadIdx.x;   // 0..4095
    const int lane = t & 63;
    const int db = (t >> 6) & 1;
    const int ct = t >> 7;                          // 0..31
    const int c  = ct * 16 + (lane & 15);
    const int d0 = db * 32 + (lane >> 4) * 8;
    const float* src = emb_w + (size_t)c * DIM + d0;
    bfrag f0, f1, f2;
#pragma unroll
    for (int j = 0; j < 8; ++j) {
        short a, b, cc;
        split3(src[j], a, b, cc);
        f0[j] = a; f1[j] = b; f2[j] = cc;
    }
    const int base = (ct * 2 + db) * 3;
    epack[(base + 0) * 64 + lane] = f0;
    epack[(base + 1) * 64 + lane] = f1;
    epack[(base + 2) * 64 + lane] = f2;
}

// ---------------------------------------------------------------------------
// Kernel 1: distance argmin via 6-pass split-bf16 MFMA (f32-accurate), fused
// with enc zero-streaming + one-hot, idx, counts, dw.
//
// Block = 256 thr = 4 waves; wave owns 64 vectors (4 row-tiles of 16).
// Per ct (16 codes): 48 MFMA 16x16x32 (4 rt x 2 db x 6 split-pairs).
// dist = ||e||^2 - 2*dot  (dropping per-vector ||x||^2: constant per row,
// argmin-order preserved). Tie rule: ascending scan + strict <, cross-lane
// combine prefers smaller k == numpy first-min.
// enc rows zero-streamed through the ct loop (float2: enc base is 8B-aligned),
// 1.0 stores after __syncthreads (vmcnt drain orders them at L2).
// ---------------------------------------------------------------------------
__global__ __launch_bounds__(256) void argmin_mfma_kernel(
    const float* __restrict__ inputs,
    const bfrag* __restrict__ epack,
    const float* __restrict__ eeg,
    int* __restrict__ idx,
    float* __restrict__ counts,
    float* __restrict__ dw,
    float* __restrict__ enc)
{
    __shared__ int sBK[256];

    const int t = threadIdx.x;
    const int w = t >> 6;
    const int lane = t & 63;
    const int r16 = lane & 15;
    const int quad = lane >> 4;
    const size_t v0 = (size_t)blockIdx.x * 256 + w * 64;   // wave's 64 vectors

    // ---- load + exact-split X into A-fragments ----
    bfrag xf[4][2][3];
#pragma unroll
    for (int rt = 0; rt < 4; ++rt)
#pragma unroll
        for (int db = 0; db < 2; ++db) {
            const float* src = inputs + (v0 + rt * 16 + r16) * DIM + db * 32 + quad * 8;
            const float4 va = *reinterpret_cast<const float4*>(src);
            const float4 vb = *reinterpret_cast<const float4*>(src + 4);
            float vals[8] = {va.x, va.y, va.z, va.w, vb.x, vb.y, vb.z, vb.w};
            bfrag f0, f1, f2;
#pragma unroll
            for (int j = 0; j < 8; ++j) {
                short a, b, c;
                split3(vals[j], a, b, c);
                f0[j] = a; f1[j] = b; f2[j] = c;
            }
            xf[rt][db][0] = f0; xf[rt][db][1] = f1; xf[rt][db][2] = f2;
        }

    float best[4][4];
    int bestk[4][4];
#pragma unroll
    for (int a = 0; a < 4; ++a)
#pragma unroll
        for (int b = 0; b < 4; ++b) { best[a][b] = 3.4e38f; bestk[a][b] = 0; }

    float* encW = enc + v0 * K_CODES;

    for (int ct = 0; ct < 32; ++ct) {
        // B-fragments for this 16-code tile (global, L2-hot, lane-packed)
        bfrag e[2][3];
#pragma unroll
        for (int db = 0; db < 2; ++db)
#pragma unroll
            for (int s = 0; s < 3; ++s)
                e[db][s] = epack[((ct * 2 + db) * 3 + s) * 64 + lane];
        const float eel = eeg[ct * 16 + r16];

        ffrag acc[4];
#pragma unroll
        for (int rt = 0; rt < 4; ++rt) acc[rt] = (ffrag){0.f, 0.f, 0.f, 0.f};

#pragma unroll
        for (int db = 0; db < 2; ++db)
#pragma unroll
            for (int rt = 0; rt < 4; ++rt) {
                acc[rt] = __builtin_amdgcn_mfma_f32_16x16x32_bf16(xf[rt][db][0], e[db][0], acc[rt], 0, 0, 0);
                acc[rt] = __builtin_amdgcn_mfma_f32_16x16x32_bf16(xf[rt][db][0], e[db][1], acc[rt], 0, 0, 0);
                acc[rt] = __builtin_amdgcn_mfma_f32_16x16x32_bf16(xf[rt][db][1], e[db][0], acc[rt], 0, 0, 0);
                acc[rt] = __builtin_amdgcn_mfma_f32_16x16x32_bf16(xf[rt][db][0], e[db][2], acc[rt], 0, 0, 0);
                acc[rt] = __builtin_amdgcn_mfma_f32_16x16x32_bf16(xf[rt][db][2], e[db][0], acc[rt], 0, 0, 0);
                acc[rt] = __builtin_amdgcn_mfma_f32_16x16x32_bf16(xf[rt][db][1], e[db][1], acc[rt], 0, 0, 0);
            }

        // ---- zero-stream 2 enc rows (4 KB) as 8 contiguous 512B wave-stores
#pragma unroll
        for (int j = 0; j < 8; ++j) {
            *reinterpret_cast<float2*>(
                encW + (size_t)(ct * 2 + (j >> 2)) * K_CODES + (j & 3) * 128 + lane * 2)
                = make_float2(0.f, 0.f);
        }

        // ---- distances + running argmin (code = ct*16 + r16, ascending) ----
        const int kc = ct * 16 + r16;
#pragma unroll
        for (int rt = 0; rt < 4; ++rt)
#pragma unroll
            for (int rg = 0; rg < 4; ++rg) {
                const float dist = fmaf(-2.f, acc[rt][rg], eel);
                if (dist < best[rt][rg]) { best[rt][rg] = dist; bestk[rt][rg] = kc; }
            }
    }

    // ---- cross-lane argmin over the 16-lane code groups ----
#pragma unroll
    for (int rt = 0; rt < 4; ++rt)
#pragma unroll
        for (int rg = 0; rg < 4; ++rg) {
            float b = best[rt][rg];
            int k = bestk[rt][rg];
#pragma unroll
            for (int m = 1; m < 16; m <<= 1) {
                const float ob = __shfl_xor(b, m, 64);
                const int ok = __shfl_xor(k, m, 64);
                if (ob < b || (ob == b && ok < k)) { b = ob; k = ok; }
            }
            best[rt][rg] = b; bestk[rt][rg] = k;
        }

    if (r16 == 0) {
#pragma unroll
        for (int rt = 0; rt < 4; ++rt)
#pragma unroll
            for (int rg = 0; rg < 4; ++rg)
                sBK[w * 64 + rt * 16 + quad * 4 + rg] = bestk[rt][rg];
    }
    __syncthreads();   // drains vmcnt (zeros committed to L2) + shares sBK

    if (r16 == 0) {
#pragma unroll
        for (int rt = 0; rt < 4; ++rt)
#pragma unroll
            for (int rg = 0; rg < 4; ++rg) {
                const int v = rt * 16 + quad * 4 + rg;
                const int k = bestk[rt][rg];
                idx[v0 + v] = k;
                atomicAdd(&counts[k], 1.0f);
                enc[(v0 + v) * (size_t)K_CODES + k] = 1.0f;
            }
    }

    // ---- dw segment-sum: contiguous 256B row atomics, x reloaded (L2-hot)
    const float* xin = inputs + v0 * DIM;
    for (int v = 0; v < 64; ++v) {
        const int k = sBK[w * 64 + v];
        atomicAdd(&dw[(size_t)k * DIM + lane], xin[v * DIM + lane]);
    }
}

// ---------------------------------------------------------------------------
// Kernel 2: EMA update + Laplace smoothing + codebook + perplexity.
// ---------------------------------------------------------------------------
__global__ __launch_bounds__(512) void ema_update_kernel(
    const float* __restrict__ counts,
    const float* __restrict__ ema_cs,
    const float* __restrict__ ema_w,
    const float* __restrict__ dw,
    float* __restrict__ new_emb,
    float* __restrict__ perp_out)
{
    __shared__ float red[K_CODES];
    const int k = threadIdx.x;

    const float cnt = counts[k];
    float cs = ema_cs[k] * 0.99f + 0.01f * cnt;

    red[k] = cs;
    __syncthreads();
    for (int s = K_CODES / 2; s > 0; s >>= 1) {
        if (k < s) red[k] += red[k + s];
        __syncthreads();
    }
    const float n = red[0];
    __syncthreads();

    cs = (cs + 1e-5f) / (n + (float)K_CODES * 1e-5f) * n;

    for (int d = 0; d < DIM; ++d) {
        const float v = ema_w[k * DIM + d] * 0.99f + 0.01f * dw[k * DIM + d];
        new_emb[k * DIM + d] = v / cs;
    }

    const float p = cnt * (1.0f / (float)N_VEC);
    red[k] = p * logf(p + 1e-10f);
    __syncthreads();
    for (int s = K_CODES / 2; s > 0; s >>= 1) {
        if (k < s) red[k] += red[k + s];
        __syncthreads();
    }
    if (k == 0) perp_out[0] = expf(-red[0]);
}

// ---------------------------------------------------------------------------
// Kernel 3: gather + straight-through + NHWC->NCHW + commitment loss.
// ---------------------------------------------------------------------------
__global__ __launch_bounds__(256) void quantize_kernel(
    const float* __restrict__ inputs,
    const int* __restrict__ idx,
    const float* __restrict__ new_emb,
    float* __restrict__ out_q,
    float* __restrict__ loss_accum)
{
    __shared__ int sIdx[64];
    __shared__ float tile[DIM][65];
    __shared__ float wsum[4];

    const int bh = blockIdx.x;
    const int b = bh >> 6, h = bh & 63;
    const int t = threadIdx.x;

    if (t < 64) sIdx[t] = idx[bh * 64 + t];
    __syncthreads();

    const float* inRow = inputs + (size_t)bh * 64 * DIM;
    const int d = t & 63;
    const int wg = t >> 6;
    float lsum = 0.f;
#pragma unroll
    for (int p = 0; p < 16; ++p) {
        const int w = wg * 16 + p;
        const float xv = inRow[w * DIM + d];
        const float qv = new_emb[sIdx[w] * DIM + d];
        const float diff = qv - xv;
        tile[d][w] = xv + diff;
        lsum = fmaf(diff, diff, lsum);
    }
    __syncthreads();

    const int w2 = t & 63;
    const int dg = t >> 6;
#pragma unroll
    for (int p = 0; p < 16; ++p) {
        const int d2 = dg * 16 + p;
        out_q[(((size_t)b * DIM + d2) * 64 + h) * 64 + w2] = tile[d2][w2];
    }

    for (int off = 32; off > 0; off >>= 1) lsum += __shfl_down(lsum, off);
    if ((t & 63) == 0) wsum[t >> 6] = lsum;
    __syncthreads();
    if (t == 0) atomicAdd(loss_accum, (wsum[0] + wsum[1]) + (wsum[2] + wsum[3]));
}

__global__ void finalize_kernel(const float* __restrict__ loss_accum,
                                float* __restrict__ out_loss)
{
    out_loss[0] = 0.25f * (loss_accum[0] / 8388608.0f);
}

// ---------------------------------------------------------------------------
extern "C" void kernel_launch(void* const* d_in, const int* in_sizes, int n_in,
                              void* d_out, int out_size, void* d_ws, size_t ws_size,
                              hipStream_t stream)
{
    const float* inputs = (const float*)d_in[0];
    const float* emb_w  = (const float*)d_in[1];
    const float* ema_cs = (const float*)d_in[2];
    const float* ema_w  = (const float*)d_in[3];
    float* out = (float*)d_out;
    float* ws  = (float*)d_ws;

    // ws layout (f32 offsets):
    int*   idxbuf = (int*)ws;            // [0, 131072)
    float* counts = ws + 131072;         // [131072, 131584)
    float* dwbuf  = ws + 131584;         // [131584, 164352)
    float* lossac = ws + 164352;         // [164352]
    float* nemb   = ws + 164353;         // [164353, 197121)
    float* eebuf  = nemb;                // overlay: consumed before ema writes
    bfrag* epack  = (bfrag*)(ws + 197124); // 192 KB, 16B-aligned

    // zero counts|dw|lossac (133 KB)
    hipMemsetAsync(counts, 0, (512 + 512 * DIM + 1) * sizeof(float), stream);

    ee_kernel<<<K_CODES / 64, 64, 0, stream>>>(emb_w, eebuf);
    epack_kernel<<<16, 256, 0, stream>>>(emb_w, epack);

    argmin_mfma_kernel<<<N_VEC / 256, 256, 0, stream>>>(
        inputs, epack, eebuf, idxbuf, counts, dwbuf, out + ENC_OFF);

    ema_update_kernel<<<1, K_CODES, 0, stream>>>(
        counts, ema_cs, ema_w, dwbuf, nemb, out + PERP_OFF);

    quantize_kernel<<<32 * 64, 256, 0, stream>>>(
        inputs, idxbuf, nemb, out + Q_OFF, lossac);

    finalize_kernel<<<1, 1, 0, stream>>>(lossac, out);
}

// Round 6
// 316.785 us; speedup vs baseline: 1.5943x; 1.0128x over previous
//
#include <hip/hip_runtime.h>

#define DIM 64
#define K_CODES 512
#define N_VEC 131072
#define Q_OFF 1
#define PERP_OFF 8388609
#define ENC_OFF 8388610

using bfrag = __attribute__((ext_vector_type(8))) short;  // 8 bf16 = 4 VGPR
using ffrag = __attribute__((ext_vector_type(4))) float;  // 4 f32 acc

// Exact 3-way bf16 truncation split: x == x0 + x1 + x2 (24 = 8+8+8 mantissa
// bits; each subtraction is exact by the Sterbenz/bit-clearing argument).
__device__ __forceinline__ void split3(float x, short& h0, short& h1, short& h2)
{
    unsigned u0 = __float_as_uint(x);
    h0 = (short)(u0 >> 16);
    float r = x - __uint_as_float(u0 & 0xFFFF0000u);     // exact
    unsigned u1 = __float_as_uint(r);
    h1 = (short)(u1 >> 16);
    float r2 = r - __uint_as_float(u1 & 0xFFFF0000u);    // exact
    h2 = (short)(__float_as_uint(r2) >> 16);             // r2 fits bf16 exactly
}

// ---------------------------------------------------------------------------
// Kernel 0a: ||e||^2 per code.
// ---------------------------------------------------------------------------
__global__ __launch_bounds__(64) void ee_kernel(const float* __restrict__ emb_w,
                                                float* __restrict__ ee)
{
    const int k = blockIdx.x * 64 + threadIdx.x;
    const float4* e4 = reinterpret_cast<const float4*>(emb_w + (size_t)k * DIM);
    float s0 = 0, s1 = 0, s2 = 0, s3 = 0;
#pragma unroll
    for (int d4 = 0; d4 < 16; ++d4) {
        const float4 v = e4[d4];
        s0 = fmaf(v.x, v.x, s0); s1 = fmaf(v.y, v.y, s1);
        s2 = fmaf(v.z, v.z, s2); s3 = fmaf(v.w, v.w, s3);
    }
    ee[k] = (s0 + s1) + (s2 + s3);
}

// ---------------------------------------------------------------------------
// Kernel 0b: pre-split + pre-pack codebook into per-lane MFMA B-fragments.
// epack[((ct*2+db)*3 + s)*64 + lane] = 8 bf16 of split s for
//   code c = ct*16 + (lane&15), d = db*32 + (lane>>4)*8 + 0..7.
// 4096 threads; output 192 KB (stays L2-hot for the main kernel).
// ---------------------------------------------------------------------------
__global__ __launch_bounds__(256) void epack_kernel(const float* __restrict__ emb_w,
                                                    bfrag* __restrict__ epack)
{
    const int t = blockIdx.x * 256 + threadIdx.x;   // 0..4095
    const int lane = t & 63;
    const int db = (t >> 6) & 1;
    const int ct = t >> 7;                          // 0..31
    const int c  = ct * 16 + (lane & 15);
    const int d0 = db * 32 + (lane >> 4) * 8;
    const float* src = emb_w + (size_t)c * DIM + d0;
    bfrag f0, f1, f2;
#pragma unroll
    for (int j = 0; j < 8; ++j) {
        short a, b, cc;
        split3(src[j], a, b, cc);
        f0[j] = a; f1[j] = b; f2[j] = cc;
    }
    const int base = (ct * 2 + db) * 3;
    epack[(base + 0) * 64 + lane] = f0;
    epack[(base + 1) * 64 + lane] = f1;
    epack[(base + 2) * 64 + lane] = f2;
}

// ---------------------------------------------------------------------------
// Kernel 1: distance argmin via 6-pass split-bf16 MFMA (f32-accurate), fused
// with enc zero-streaming + one-hot, idx, counts, dw.
//
// Block = 256 thr = 4 waves; wave owns 64 vectors (4 row-tiles of 16).
// Per ct (16 codes): 48 MFMA 16x16x32 (4 rt x 2 db x 6 split-pairs).
// dist = ||e||^2 - 2*dot  (dropping per-vector ||x||^2: constant per row,
// argmin-order preserved). Tie rule: ascending scan + strict <, cross-lane
// combine prefers smaller k == numpy first-min.
// enc rows zero-streamed through the ct loop (float2: enc base is 8B-aligned),
// 1.0 stores after __syncthreads (vmcnt drain orders them at L2).
// ---------------------------------------------------------------------------
__global__ __launch_bounds__(256) void argmin_mfma_kernel(
    const float* __restrict__ inputs,
    const bfrag* __restrict__ epack,
    const float* __restrict__ eeg,
    int* __restrict__ idx,
    float* __restrict__ counts,
    float* __restrict__ dw,
    float* __restrict__ enc)
{
    __shared__ int sBK[256];

    const int t = threadIdx.x;
    const int w = t >> 6;
    const int lane = t & 63;
    const int r16 = lane & 15;
    const int quad = lane >> 4;
    const size_t v0 = (size_t)blockIdx.x * 256 + w * 64;   // wave's 64 vectors

    // ---- load + exact-split X into A-fragments ----
    bfrag xf[4][2][3];
#pragma unroll
    for (int rt = 0; rt < 4; ++rt)
#pragma unroll
        for (int db = 0; db < 2; ++db) {
            const float* src = inputs + (v0 + rt * 16 + r16) * DIM + db * 32 + quad * 8;
            const float4 va = *reinterpret_cast<const float4*>(src);
            const float4 vb = *reinterpret_cast<const float4*>(src + 4);
            float vals[8] = {va.x, va.y, va.z, va.w, vb.x, vb.y, vb.z, vb.w};
            bfrag f0, f1, f2;
#pragma unroll
            for (int j = 0; j < 8; ++j) {
                short a, b, c;
                split3(vals[j], a, b, c);
                f0[j] = a; f1[j] = b; f2[j] = c;
            }
            xf[rt][db][0] = f0; xf[rt][db][1] = f1; xf[rt][db][2] = f2;
        }

    float best[4][4];
    int bestk[4][4];
#pragma unroll
    for (int a = 0; a < 4; ++a)
#pragma unroll
        for (int b = 0; b < 4; ++b) { best[a][b] = 3.4e38f; bestk[a][b] = 0; }

    float* encW = enc + v0 * K_CODES;

    for (int ct = 0; ct < 32; ++ct) {
        // B-fragments for this 16-code tile (global, L2-hot, lane-packed)
        bfrag e[2][3];
#pragma unroll
        for (int db = 0; db < 2; ++db)
#pragma unroll
            for (int s = 0; s < 3; ++s)
                e[db][s] = epack[((ct * 2 + db) * 3 + s) * 64 + lane];
        const float eel = eeg[ct * 16 + r16];

        ffrag acc[4];
#pragma unroll
        for (int rt = 0; rt < 4; ++rt) acc[rt] = (ffrag){0.f, 0.f, 0.f, 0.f};

#pragma unroll
        for (int db = 0; db < 2; ++db)
#pragma unroll
            for (int rt = 0; rt < 4; ++rt) {
                acc[rt] = __builtin_amdgcn_mfma_f32_16x16x32_bf16(xf[rt][db][0], e[db][0], acc[rt], 0, 0, 0);
                acc[rt] = __builtin_amdgcn_mfma_f32_16x16x32_bf16(xf[rt][db][0], e[db][1], acc[rt], 0, 0, 0);
                acc[rt] = __builtin_amdgcn_mfma_f32_16x16x32_bf16(xf[rt][db][1], e[db][0], acc[rt], 0, 0, 0);
                acc[rt] = __builtin_amdgcn_mfma_f32_16x16x32_bf16(xf[rt][db][0], e[db][2], acc[rt], 0, 0, 0);
                acc[rt] = __builtin_amdgcn_mfma_f32_16x16x32_bf16(xf[rt][db][2], e[db][0], acc[rt], 0, 0, 0);
                acc[rt] = __builtin_amdgcn_mfma_f32_16x16x32_bf16(xf[rt][db][1], e[db][1], acc[rt], 0, 0, 0);
            }

        // ---- zero-stream 2 enc rows (4 KB) as 8 contiguous 512B wave-stores
#pragma unroll
        for (int j = 0; j < 8; ++j) {
            *reinterpret_cast<float2*>(
                encW + (size_t)(ct * 2 + (j >> 2)) * K_CODES + (j & 3) * 128 + lane * 2)
                = make_float2(0.f, 0.f);
        }

        // ---- distances + running argmin (code = ct*16 + r16, ascending) ----
        const int kc = ct * 16 + r16;
#pragma unroll
        for (int rt = 0; rt < 4; ++rt)
#pragma unroll
            for (int rg = 0; rg < 4; ++rg) {
                const float dist = fmaf(-2.f, acc[rt][rg], eel);
                if (dist < best[rt][rg]) { best[rt][rg] = dist; bestk[rt][rg] = kc; }
            }
    }

    // ---- cross-lane argmin over the 16-lane code groups ----
#pragma unroll
    for (int rt = 0; rt < 4; ++rt)
#pragma unroll
        for (int rg = 0; rg < 4; ++rg) {
            float b = best[rt][rg];
            int k = bestk[rt][rg];
#pragma unroll
            for (int m = 1; m < 16; m <<= 1) {
                const float ob = __shfl_xor(b, m, 64);
                const int ok = __shfl_xor(k, m, 64);
                if (ob < b || (ob == b && ok < k)) { b = ob; k = ok; }
            }
            best[rt][rg] = b; bestk[rt][rg] = k;
        }

    if (r16 == 0) {
#pragma unroll
        for (int rt = 0; rt < 4; ++rt)
#pragma unroll
            for (int rg = 0; rg < 4; ++rg)
                sBK[w * 64 + rt * 16 + quad * 4 + rg] = bestk[rt][rg];
    }
    __syncthreads();   // drains vmcnt (zeros committed to L2) + shares sBK

    if (r16 == 0) {
#pragma unroll
        for (int rt = 0; rt < 4; ++rt)
#pragma unroll
            for (int rg = 0; rg < 4; ++rg) {
                const int v = rt * 16 + quad * 4 + rg;
                const int k = bestk[rt][rg];
                idx[v0 + v] = k;
                atomicAdd(&counts[k], 1.0f);
                enc[(v0 + v) * (size_t)K_CODES + k] = 1.0f;
            }
    }

    // ---- dw segment-sum: contiguous 256B row atomics, x reloaded (L2-hot)
    const float* xin = inputs + v0 * DIM;
    for (int v = 0; v < 64; ++v) {
        const int k = sBK[w * 64 + v];
        atomicAdd(&dw[(size_t)k * DIM + lane], xin[v * DIM + lane]);
    }
}

// ---------------------------------------------------------------------------
// Kernel 2: EMA update + Laplace smoothing + codebook + perplexity.
// ---------------------------------------------------------------------------
__global__ __launch_bounds__(512) void ema_update_kernel(
    const float* __restrict__ counts,
    const float* __restrict__ ema_cs,
    const float* __restrict__ ema_w,
    const float* __restrict__ dw,
    float* __restrict__ new_emb,
    float* __restrict__ perp_out)
{
    __shared__ float red[K_CODES];
    const int k = threadIdx.x;

    const float cnt = counts[k];
    float cs = ema_cs[k] * 0.99f + 0.01f * cnt;

    red[k] = cs;
    __syncthreads();
    for (int s = K_CODES / 2; s > 0; s >>= 1) {
        if (k < s) red[k] += red[k + s];
        __syncthreads();
    }
    const float n = red[0];
    __syncthreads();

    cs = (cs + 1e-5f) / (n + (float)K_CODES * 1e-5f) * n;

    for (int d = 0; d < DIM; ++d) {
        const float v = ema_w[k * DIM + d] * 0.99f + 0.01f * dw[k * DIM + d];
        new_emb[k * DIM + d] = v / cs;
    }

    const float p = cnt * (1.0f / (float)N_VEC);
    red[k] = p * logf(p + 1e-10f);
    __syncthreads();
    for (int s = K_CODES / 2; s > 0; s >>= 1) {
        if (k < s) red[k] += red[k + s];
        __syncthreads();
    }
    if (k == 0) perp_out[0] = expf(-red[0]);
}

// ---------------------------------------------------------------------------
// Kernel 3: gather + straight-through + NHWC->NCHW + commitment loss.
// ---------------------------------------------------------------------------
__global__ __launch_bounds__(256) void quantize_kernel(
    const float* __restrict__ inputs,
    const int* __restrict__ idx,
    const float* __restrict__ new_emb,
    float* __restrict__ out_q,
    float* __restrict__ loss_accum)
{
    __shared__ int sIdx[64];
    __shared__ float tile[DIM][65];
    __shared__ float wsum[4];

    const int bh = blockIdx.x;
    const int b = bh >> 6, h = bh & 63;
    const int t = threadIdx.x;

    if (t < 64) sIdx[t] = idx[bh * 64 + t];
    __syncthreads();

    const float* inRow = inputs + (size_t)bh * 64 * DIM;
    const int d = t & 63;
    const int wg = t >> 6;
    float lsum = 0.f;
#pragma unroll
    for (int p = 0; p < 16; ++p) {
        const int w = wg * 16 + p;
        const float xv = inRow[w * DIM + d];
        const float qv = new_emb[sIdx[w] * DIM + d];
        const float diff = qv - xv;
        tile[d][w] = xv + diff;
        lsum = fmaf(diff, diff, lsum);
    }
    __syncthreads();

    const int w2 = t & 63;
    const int dg = t >> 6;
#pragma unroll
    for (int p = 0; p < 16; ++p) {
        const int d2 = dg * 16 + p;
        out_q[(((size_t)b * DIM + d2) * 64 + h) * 64 + w2] = tile[d2][w2];
    }

    for (int off = 32; off > 0; off >>= 1) lsum += __shfl_down(lsum, off);
    if ((t & 63) == 0) wsum[t >> 6] = lsum;
    __syncthreads();
    if (t == 0) atomicAdd(loss_accum, (wsum[0] + wsum[1]) + (wsum[2] + wsum[3]));
}

__global__ void finalize_kernel(const float* __restrict__ loss_accum,
                                float* __restrict__ out_loss)
{
    out_loss[0] = 0.25f * (loss_accum[0] / 8388608.0f);
}

// ---------------------------------------------------------------------------
extern "C" void kernel_launch(void* const* d_in, const int* in_sizes, int n_in,
                              void* d_out, int out_size, void* d_ws, size_t ws_size,
                              hipStream_t stream)
{
    const float* inputs = (const float*)d_in[0];
    const float* emb_w  = (const float*)d_in[1];
    const float* ema_cs = (const float*)d_in[2];
    const float* ema_w  = (const float*)d_in[3];
    float* out = (float*)d_out;
    float* ws  = (float*)d_ws;

    // ws layout (f32 offsets):
    int*   idxbuf = (int*)ws;            // [0, 131072)
    float* counts = ws + 131072;         // [131072, 131584)
    float* dwbuf  = ws + 131584;         // [131584, 164352)
    float* lossac = ws + 164352;         // [164352]
    float* nemb   = ws + 164353;         // [164353, 197121)
    float* eebuf  = nemb;                // overlay: consumed before ema writes
    bfrag* epack  = (bfrag*)(ws + 197124); // 192 KB, 16B-aligned

    // zero counts|dw|lossac (133 KB)
    hipMemsetAsync(counts, 0, (512 + 512 * DIM + 1) * sizeof(float), stream);

    ee_kernel<<<K_CODES / 64, 64, 0, stream>>>(emb_w, eebuf);
    epack_kernel<<<16, 256, 0, stream>>>(emb_w, epack);

    argmin_mfma_kernel<<<N_VEC / 256, 256, 0, stream>>>(
        inputs, epack, eebuf, idxbuf, counts, dwbuf, out + ENC_OFF);

    ema_update_kernel<<<1, K_CODES, 0, stream>>>(
        counts, ema_cs, ema_w, dwbuf, nemb, out + PERP_OFF);

    quantize_kernel<<<32 * 64, 256, 0, stream>>>(
        inputs, idxbuf, nemb, out + Q_OFF, lossac);

    finalize_kernel<<<1, 1, 0, stream>>>(lossac, out);
}

// Round 7
// 287.046 us; speedup vs baseline: 1.7594x; 1.1036x over previous
//
#include <hip/hip_runtime.h>

#define DIM 64
#define K_CODES 512
#define N_VEC 131072
#define Q_OFF 1
#define PERP_OFF 8388609
#define ENC_OFF 8388610

using bfrag = __attribute__((ext_vector_type(8))) short;  // 8 bf16 = 4 VGPR
using ffrag = __attribute__((ext_vector_type(4))) float;  // 4 f32 acc

// Exact 3-way bf16 truncation split: x == x0 + x1 + x2.
__device__ __forceinline__ void split3(float x, short& h0, short& h1, short& h2)
{
    unsigned u0 = __float_as_uint(x);
    h0 = (short)(u0 >> 16);
    float r = x - __uint_as_float(u0 & 0xFFFF0000u);     // exact
    unsigned u1 = __float_as_uint(r);
    h1 = (short)(u1 >> 16);
    float r2 = r - __uint_as_float(u1 & 0xFFFF0000u);    // exact
    h2 = (short)(__float_as_uint(r2) >> 16);             // r2 fits bf16 exactly
}

// ---------------------------------------------------------------------------
// Kernel 0a: ||e||^2 per code.
// ---------------------------------------------------------------------------
__global__ __launch_bounds__(64) void ee_kernel(const float* __restrict__ emb_w,
                                                float* __restrict__ ee)
{
    const int k = blockIdx.x * 64 + threadIdx.x;
    const float4* e4 = reinterpret_cast<const float4*>(emb_w + (size_t)k * DIM);
    float s0 = 0, s1 = 0, s2 = 0, s3 = 0;
#pragma unroll
    for (int d4 = 0; d4 < 16; ++d4) {
        const float4 v = e4[d4];
        s0 = fmaf(v.x, v.x, s0); s1 = fmaf(v.y, v.y, s1);
        s2 = fmaf(v.z, v.z, s2); s3 = fmaf(v.w, v.w, s3);
    }
    ee[k] = (s0 + s1) + (s2 + s3);
}

// ---------------------------------------------------------------------------
// Kernel 0b: pre-split + pre-pack codebook into per-lane MFMA B-fragments.
// epack[((ct*2+db)*3 + s)*64 + lane]: code c = ct*16 + (lane&15),
// d = db*32 + (lane>>4)*8 + 0..7, split s. 192 KB, L2-resident.
// ---------------------------------------------------------------------------
__global__ __launch_bounds__(256) void epack_kernel(const float* __restrict__ emb_w,
                                                    bfrag* __restrict__ epack)
{
    const int t = blockIdx.x * 256 + threadIdx.x;   // 0..4095
    const int lane = t & 63;
    const int db = (t >> 6) & 1;
    const int ct = t >> 7;                          // 0..31
    const int c  = ct * 16 + (lane & 15);
    const int d0 = db * 32 + (lane >> 4) * 8;
    const float* src = emb_w + (size_t)c * DIM + d0;
    bfrag f0, f1, f2;
#pragma unroll
    for (int j = 0; j < 8; ++j) {
        short a, b, cc;
        split3(src[j], a, b, cc);
        f0[j] = a; f1[j] = b; f2[j] = cc;
    }
    const int base = (ct * 2 + db) * 3;
    epack[(base + 0) * 64 + lane] = f0;
    epack[(base + 1) * 64 + lane] = f1;
    epack[(base + 2) * 64 + lane] = f2;
}

// ---------------------------------------------------------------------------
// Kernel 1: distance argmin via 6-pass split-bf16 MFMA, spill-free config.
// Wave owns 32 vectors (2 row-tiles); block = 4 waves = 128 vectors;
// grid = 1024. B-fragments double-buffered in registers (prefetch ct+1
// during ct's MFMAs). MFMA order alternates the 2 acc chains.
// Fused: enc zero-stream (1 row/ct, 4x512B wave-stores) + one-hot 1.0,
// idx, counts, dw row atomics.
// Tie rule: ascending scan + strict <, cross-lane prefers smaller k.
// ---------------------------------------------------------------------------
__global__ __launch_bounds__(256, 1) void argmin_mfma_kernel(
    const float* __restrict__ inputs,
    const bfrag* __restrict__ epack,
    const float* __restrict__ eeg,
    int* __restrict__ idx,
    float* __restrict__ counts,
    float* __restrict__ dw,
    float* __restrict__ enc)
{
    __shared__ int sBK[128];

    const int t = threadIdx.x;
    const int w = t >> 6;
    const int lane = t & 63;
    const int r16 = lane & 15;
    const int quad = lane >> 4;
    const size_t v0 = (size_t)blockIdx.x * 128 + w * 32;   // wave's 32 vectors

    // ---- load + exact-split X into A-fragments (48 VGPRs) ----
    bfrag xf[2][2][3];
#pragma unroll
    for (int rt = 0; rt < 2; ++rt)
#pragma unroll
        for (int db = 0; db < 2; ++db) {
            const float* src = inputs + (v0 + rt * 16 + r16) * DIM + db * 32 + quad * 8;
            const float4 va = *reinterpret_cast<const float4*>(src);
            const float4 vb = *reinterpret_cast<const float4*>(src + 4);
            float vals[8] = {va.x, va.y, va.z, va.w, vb.x, vb.y, vb.z, vb.w};
            bfrag f0, f1, f2;
#pragma unroll
            for (int j = 0; j < 8; ++j) {
                short a, b, c;
                split3(vals[j], a, b, c);
                f0[j] = a; f1[j] = b; f2[j] = c;
            }
            xf[rt][db][0] = f0; xf[rt][db][1] = f1; xf[rt][db][2] = f2;
        }

    float best[2][4];
    int bestk[2][4];
#pragma unroll
    for (int a = 0; a < 2; ++a)
#pragma unroll
        for (int b = 0; b < 4; ++b) { best[a][b] = 3.4e38f; bestk[a][b] = 0; }

    float* encW = enc + v0 * K_CODES;

    // product order (i,j) with i+j<=2
    constexpr int PI[6] = {0, 0, 1, 0, 2, 1};
    constexpr int PJ[6] = {0, 1, 0, 2, 0, 1};

    // ---- prefetch ct=0 B-fragments ----
    bfrag eC[2][3];
    float eelC;
#pragma unroll
    for (int db = 0; db < 2; ++db)
#pragma unroll
        for (int s = 0; s < 3; ++s)
            eC[db][s] = epack[(db * 3 + s) * 64 + lane];
    eelC = eeg[r16];

    for (int ct = 0; ct < 32; ++ct) {
        // ---- prefetch ct+1 (hides L2 latency under this ct's MFMAs) ----
        bfrag eN[2][3];
        float eelN = 0.f;
        if (ct < 31) {
#pragma unroll
            for (int db = 0; db < 2; ++db)
#pragma unroll
                for (int s = 0; s < 3; ++s)
                    eN[db][s] = epack[(((ct + 1) * 2 + db) * 3 + s) * 64 + lane];
            eelN = eeg[(ct + 1) * 16 + r16];
        }

        // ---- 24 MFMAs, 2 chains interleaved ----
        ffrag acc[2];
        acc[0] = (ffrag){0.f, 0.f, 0.f, 0.f};
        acc[1] = (ffrag){0.f, 0.f, 0.f, 0.f};
#pragma unroll
        for (int db = 0; db < 2; ++db)
#pragma unroll
            for (int p = 0; p < 6; ++p) {
                acc[0] = __builtin_amdgcn_mfma_f32_16x16x32_bf16(
                    xf[0][db][PI[p]], eC[db][PJ[p]], acc[0], 0, 0, 0);
                acc[1] = __builtin_amdgcn_mfma_f32_16x16x32_bf16(
                    xf[1][db][PI[p]], eC[db][PJ[p]], acc[1], 0, 0, 0);
            }

        // ---- zero-stream one enc row (2 KB) as 4 contiguous 512B stores ----
        {
            float2* rp = reinterpret_cast<float2*>(encW + (size_t)ct * K_CODES);
#pragma unroll
            for (int j = 0; j < 4; ++j)
                rp[j * 64 + lane] = make_float2(0.f, 0.f);
        }

        // ---- distances + running argmin (code = ct*16 + r16) ----
        const int kc = ct * 16 + r16;
#pragma unroll
        for (int rt = 0; rt < 2; ++rt)
#pragma unroll
            for (int rg = 0; rg < 4; ++rg) {
                const float dist = fmaf(-2.f, acc[rt][rg], eelC);
                if (dist < best[rt][rg]) { best[rt][rg] = dist; bestk[rt][rg] = kc; }
            }

        // ---- rotate prefetch buffers ----
#pragma unroll
        for (int db = 0; db < 2; ++db)
#pragma unroll
            for (int s = 0; s < 3; ++s)
                eC[db][s] = eN[db][s];
        eelC = eelN;
    }

    // ---- cross-lane argmin over the 16-lane code groups ----
#pragma unroll
    for (int rt = 0; rt < 2; ++rt)
#pragma unroll
        for (int rg = 0; rg < 4; ++rg) {
            float b = best[rt][rg];
            int k = bestk[rt][rg];
#pragma unroll
            for (int m = 1; m < 16; m <<= 1) {
                const float ob = __shfl_xor(b, m, 64);
                const int ok = __shfl_xor(k, m, 64);
                if (ob < b || (ob == b && ok < k)) { b = ob; k = ok; }
            }
            bestk[rt][rg] = k;
        }

    if (r16 == 0) {
#pragma unroll
        for (int rt = 0; rt < 2; ++rt)
#pragma unroll
            for (int rg = 0; rg < 4; ++rg)
                sBK[w * 32 + rt * 16 + quad * 4 + rg] = bestk[rt][rg];
    }
    __syncthreads();   // drains vmcnt (zeros committed) + publishes sBK

    if (r16 == 0) {
#pragma unroll
        for (int rt = 0; rt < 2; ++rt)
#pragma unroll
            for (int rg = 0; rg < 4; ++rg) {
                const int v = rt * 16 + quad * 4 + rg;
                const int k = bestk[rt][rg];
                idx[v0 + v] = k;
                atomicAdd(&counts[k], 1.0f);
                enc[(v0 + v) * (size_t)K_CODES + k] = 1.0f;
            }
    }

    // ---- dw segment-sum: contiguous 256B row atomics, x reloaded (L2-hot) ----
    const float* xin = inputs + v0 * DIM;
#pragma unroll 4
    for (int v = 0; v < 32; ++v) {
        const int k = sBK[w * 32 + v];
        atomicAdd(&dw[(size_t)k * DIM + lane], xin[v * DIM + lane]);
    }
}

// ---------------------------------------------------------------------------
// Kernel 2: EMA update + Laplace smoothing + codebook + perplexity.
// ---------------------------------------------------------------------------
__global__ __launch_bounds__(512) void ema_update_kernel(
    const float* __restrict__ counts,
    const float* __restrict__ ema_cs,
    const float* __restrict__ ema_w,
    const float* __restrict__ dw,
    float* __restrict__ new_emb,
    float* __restrict__ perp_out)
{
    __shared__ float red[K_CODES];
    const int k = threadIdx.x;

    const float cnt = counts[k];
    float cs = ema_cs[k] * 0.99f + 0.01f * cnt;

    red[k] = cs;
    __syncthreads();
    for (int s = K_CODES / 2; s > 0; s >>= 1) {
        if (k < s) red[k] += red[k + s];
        __syncthreads();
    }
    const float n = red[0];
    __syncthreads();

    cs = (cs + 1e-5f) / (n + (float)K_CODES * 1e-5f) * n;

    for (int d = 0; d < DIM; ++d) {
        const float v = ema_w[k * DIM + d] * 0.99f + 0.01f * dw[k * DIM + d];
        new_emb[k * DIM + d] = v / cs;
    }

    const float p = cnt * (1.0f / (float)N_VEC);
    red[k] = p * logf(p + 1e-10f);
    __syncthreads();
    for (int s = K_CODES / 2; s > 0; s >>= 1) {
        if (k < s) red[k] += red[k + s];
        __syncthreads();
    }
    if (k == 0) perp_out[0] = expf(-red[0]);
}

// ---------------------------------------------------------------------------
// Kernel 3: gather + straight-through + NHWC->NCHW + commitment loss.
// ---------------------------------------------------------------------------
__global__ __launch_bounds__(256) void quantize_kernel(
    const float* __restrict__ inputs,
    const int* __restrict__ idx,
    const float* __restrict__ new_emb,
    float* __restrict__ out_q,
    float* __restrict__ loss_accum)
{
    __shared__ int sIdx[64];
    __shared__ float tile[DIM][65];
    __shared__ float wsum[4];

    const int bh = blockIdx.x;
    const int b = bh >> 6, h = bh & 63;
    const int t = threadIdx.x;

    if (t < 64) sIdx[t] = idx[bh * 64 + t];
    __syncthreads();

    const float* inRow = inputs + (size_t)bh * 64 * DIM;
    const int d = t & 63;
    const int wg = t >> 6;
    float lsum = 0.f;
#pragma unroll
    for (int p = 0; p < 16; ++p) {
        const int w = wg * 16 + p;
        const float xv = inRow[w * DIM + d];
        const float qv = new_emb[sIdx[w] * DIM + d];
        const float diff = qv - xv;
        tile[d][w] = xv + diff;
        lsum = fmaf(diff, diff, lsum);
    }
    __syncthreads();

    const int w2 = t & 63;
    const int dg = t >> 6;
#pragma unroll
    for (int p = 0; p < 16; ++p) {
        const int d2 = dg * 16 + p;
        out_q[(((size_t)b * DIM + d2) * 64 + h) * 64 + w2] = tile[d2][w2];
    }

    for (int off = 32; off > 0; off >>= 1) lsum += __shfl_down(lsum, off);
    if ((t & 63) == 0) wsum[t >> 6] = lsum;
    __syncthreads();
    if (t == 0) atomicAdd(loss_accum, (wsum[0] + wsum[1]) + (wsum[2] + wsum[3]));
}

__global__ void finalize_kernel(const float* __restrict__ loss_accum,
                                float* __restrict__ out_loss)
{
    out_loss[0] = 0.25f * (loss_accum[0] / 8388608.0f);
}

// ---------------------------------------------------------------------------
extern "C" void kernel_launch(void* const* d_in, const int* in_sizes, int n_in,
                              void* d_out, int out_size, void* d_ws, size_t ws_size,
                              hipStream_t stream)
{
    const float* inputs = (const float*)d_in[0];
    const float* emb_w  = (const float*)d_in[1];
    const float* ema_cs = (const float*)d_in[2];
    const float* ema_w  = (const float*)d_in[3];
    float* out = (float*)d_out;
    float* ws  = (float*)d_ws;

    // ws layout (f32 offsets):
    int*   idxbuf = (int*)ws;            // [0, 131072)
    float* counts = ws + 131072;         // [131072, 131584)
    float* dwbuf  = ws + 131584;         // [131584, 164352)
    float* lossac = ws + 164352;         // [164352]
    float* nemb   = ws + 164353;         // [164353, 197121)
    float* eebuf  = nemb;                // overlay: consumed before ema writes
    bfrag* epack  = (bfrag*)(ws + 197124); // 192 KB, 16B-aligned

    // zero counts|dw|lossac (133 KB)
    hipMemsetAsync(counts, 0, (512 + 512 * DIM + 1) * sizeof(float), stream);

    ee_kernel<<<K_CODES / 64, 64, 0, stream>>>(emb_w, eebuf);
    epack_kernel<<<16, 256, 0, stream>>>(emb_w, epack);

    argmin_mfma_kernel<<<N_VEC / 128, 256, 0, stream>>>(
        inputs, epack, eebuf, idxbuf, counts, dwbuf, out + ENC_OFF);

    ema_update_kernel<<<1, K_CODES, 0, stream>>>(
        counts, ema_cs, ema_w, dwbuf, nemb, out + PERP_OFF);

    quantize_kernel<<<32 * 64, 256, 0, stream>>>(
        inputs, idxbuf, nemb, out + Q_OFF, lossac);

    finalize_kernel<<<1, 1, 0, stream>>>(lossac, out);
}

// Round 8
// 226.021 us; speedup vs baseline: 2.2345x; 1.2700x over previous
//
#include <hip/hip_runtime.h>

#define DIM 64
#define K_CODES 512
#define N_VEC 131072
#define NREP 16
#define Q_OFF 1
#define PERP_OFF 8388609
#define ENC_OFF 8388610

using bfrag = __attribute__((ext_vector_type(8))) short;  // 8 bf16 = 4 VGPR
using ffrag = __attribute__((ext_vector_type(4))) float;  // 4 f32 acc

// Exact 3-way bf16 truncation split: x == x0 + x1 + x2.
__device__ __forceinline__ void split3(float x, short& h0, short& h1, short& h2)
{
    unsigned u0 = __float_as_uint(x);
    h0 = (short)(u0 >> 16);
    float r = x - __uint_as_float(u0 & 0xFFFF0000u);     // exact
    unsigned u1 = __float_as_uint(r);
    h1 = (short)(u1 >> 16);
    float r2 = r - __uint_as_float(u1 & 0xFFFF0000u);    // exact
    h2 = (short)(__float_as_uint(r2) >> 16);             // r2 fits bf16 exactly
}

// ---------------------------------------------------------------------------
// enc zero-fill: 268 MB, aligned float4 body (enc base is 8B-misaligned).
// ---------------------------------------------------------------------------
__global__ __launch_bounds__(256) void enc_zero_kernel(float* __restrict__ enc)
{
    const size_t nf4 = 16777215;                       // (67108864-2-2)/4
    float4* body = reinterpret_cast<float4*>(enc + 2); // 16B-aligned
    const size_t stride = (size_t)gridDim.x * 256;
    const float4 z = make_float4(0.f, 0.f, 0.f, 0.f);
    for (size_t i = (size_t)blockIdx.x * 256 + threadIdx.x; i < nf4; i += stride)
        body[i] = z;
    if (blockIdx.x == 0 && threadIdx.x == 0) {
        enc[0] = 0.f; enc[1] = 0.f;
        enc[67108862] = 0.f; enc[67108863] = 0.f;
    }
}

// ---------------------------------------------------------------------------
// ||e||^2 per code.
// ---------------------------------------------------------------------------
__global__ __launch_bounds__(64) void ee_kernel(const float* __restrict__ emb_w,
                                                float* __restrict__ ee)
{
    const int k = blockIdx.x * 64 + threadIdx.x;
    const float4* e4 = reinterpret_cast<const float4*>(emb_w + (size_t)k * DIM);
    float s0 = 0, s1 = 0, s2 = 0, s3 = 0;
#pragma unroll
    for (int d4 = 0; d4 < 16; ++d4) {
        const float4 v = e4[d4];
        s0 = fmaf(v.x, v.x, s0); s1 = fmaf(v.y, v.y, s1);
        s2 = fmaf(v.z, v.z, s2); s3 = fmaf(v.w, v.w, s3);
    }
    ee[k] = (s0 + s1) + (s2 + s3);
}

// ---------------------------------------------------------------------------
// pre-split + pre-pack codebook into per-lane MFMA B-fragments (192 KB).
// ---------------------------------------------------------------------------
__global__ __launch_bounds__(256) void epack_kernel(const float* __restrict__ emb_w,
                                                    bfrag* __restrict__ epack)
{
    const int t = blockIdx.x * 256 + threadIdx.x;   // 0..4095
    const int lane = t & 63;
    const int db = (t >> 6) & 1;
    const int ct = t >> 7;                          // 0..31
    const int c  = ct * 16 + (lane & 15);
    const int d0 = db * 32 + (lane >> 4) * 8;
    const float* src = emb_w + (size_t)c * DIM + d0;
    bfrag f0, f1, f2;
#pragma unroll
    for (int j = 0; j < 8; ++j) {
        short a, b, cc;
        split3(src[j], a, b, cc);
        f0[j] = a; f1[j] = b; f2[j] = cc;
    }
    const int base = (ct * 2 + db) * 3;
    epack[(base + 0) * 64 + lane] = f0;
    epack[(base + 1) * 64 + lane] = f1;
    epack[(base + 2) * 64 + lane] = f2;
}

// ---------------------------------------------------------------------------
// argmin via 6-pass split-bf16 MFMA. Wave owns 32 vectors; block 128; grid
// 1024. B-fragments double-buffered in registers. Writes: idx, one-hot 1.0
// (zeros pre-written by enc_zero), counts into 16 replicas. No barriers.
// Tie rule: ascending scan + strict <, cross-lane prefers smaller k.
// ---------------------------------------------------------------------------
__global__ __launch_bounds__(256, 1) void argmin_mfma_kernel(
    const float* __restrict__ inputs,
    const bfrag* __restrict__ epack,
    const float* __restrict__ eeg,
    int* __restrict__ idx,
    float* __restrict__ counts_rep,
    float* __restrict__ enc)
{
    const int t = threadIdx.x;
    const int w = t >> 6;
    const int lane = t & 63;
    const int r16 = lane & 15;
    const int quad = lane >> 4;
    const size_t v0 = (size_t)blockIdx.x * 128 + w * 32;

    // ---- load + exact-split X into A-fragments ----
    bfrag xf[2][2][3];
#pragma unroll
    for (int rt = 0; rt < 2; ++rt)
#pragma unroll
        for (int db = 0; db < 2; ++db) {
            const float* src = inputs + (v0 + rt * 16 + r16) * DIM + db * 32 + quad * 8;
            const float4 va = *reinterpret_cast<const float4*>(src);
            const float4 vb = *reinterpret_cast<const float4*>(src + 4);
            float vals[8] = {va.x, va.y, va.z, va.w, vb.x, vb.y, vb.z, vb.w};
            bfrag f0, f1, f2;
#pragma unroll
            for (int j = 0; j < 8; ++j) {
                short a, b, c;
                split3(vals[j], a, b, c);
                f0[j] = a; f1[j] = b; f2[j] = c;
            }
            xf[rt][db][0] = f0; xf[rt][db][1] = f1; xf[rt][db][2] = f2;
        }

    float best[2][4];
    int bestk[2][4];
#pragma unroll
    for (int a = 0; a < 2; ++a)
#pragma unroll
        for (int b = 0; b < 4; ++b) { best[a][b] = 3.4e38f; bestk[a][b] = 0; }

    constexpr int PI[6] = {0, 0, 1, 0, 2, 1};
    constexpr int PJ[6] = {0, 1, 0, 2, 0, 1};

    bfrag eC[2][3];
    float eelC;
#pragma unroll
    for (int db = 0; db < 2; ++db)
#pragma unroll
        for (int s = 0; s < 3; ++s)
            eC[db][s] = epack[(db * 3 + s) * 64 + lane];
    eelC = eeg[r16];

    for (int ct = 0; ct < 32; ++ct) {
        bfrag eN[2][3];
        float eelN = 0.f;
        if (ct < 31) {
#pragma unroll
            for (int db = 0; db < 2; ++db)
#pragma unroll
                for (int s = 0; s < 3; ++s)
                    eN[db][s] = epack[(((ct + 1) * 2 + db) * 3 + s) * 64 + lane];
            eelN = eeg[(ct + 1) * 16 + r16];
        }

        ffrag acc[2];
        acc[0] = (ffrag){0.f, 0.f, 0.f, 0.f};
        acc[1] = (ffrag){0.f, 0.f, 0.f, 0.f};
#pragma unroll
        for (int db = 0; db < 2; ++db)
#pragma unroll
            for (int p = 0; p < 6; ++p) {
                acc[0] = __builtin_amdgcn_mfma_f32_16x16x32_bf16(
                    xf[0][db][PI[p]], eC[db][PJ[p]], acc[0], 0, 0, 0);
                acc[1] = __builtin_amdgcn_mfma_f32_16x16x32_bf16(
                    xf[1][db][PI[p]], eC[db][PJ[p]], acc[1], 0, 0, 0);
            }

        const int kc = ct * 16 + r16;
#pragma unroll
        for (int rt = 0; rt < 2; ++rt)
#pragma unroll
            for (int rg = 0; rg < 4; ++rg) {
                const float dist = fmaf(-2.f, acc[rt][rg], eelC);
                if (dist < best[rt][rg]) { best[rt][rg] = dist; bestk[rt][rg] = kc; }
            }

#pragma unroll
        for (int db = 0; db < 2; ++db)
#pragma unroll
            for (int s = 0; s < 3; ++s)
                eC[db][s] = eN[db][s];
        eelC = eelN;
    }

    // ---- cross-lane argmin over the 16-lane code groups ----
#pragma unroll
    for (int rt = 0; rt < 2; ++rt)
#pragma unroll
        for (int rg = 0; rg < 4; ++rg) {
            float b = best[rt][rg];
            int k = bestk[rt][rg];
#pragma unroll
            for (int m = 1; m < 16; m <<= 1) {
                const float ob = __shfl_xor(b, m, 64);
                const int ok = __shfl_xor(k, m, 64);
                if (ob < b || (ob == b && ok < k)) { b = ob; k = ok; }
            }
            bestk[rt][rg] = k;
        }

    if (r16 == 0) {
        float* crep = counts_rep + (blockIdx.x & (NREP - 1)) * K_CODES;
#pragma unroll
        for (int rt = 0; rt < 2; ++rt)
#pragma unroll
            for (int rg = 0; rg < 4; ++rg) {
                const int v = rt * 16 + quad * 4 + rg;
                const int k = bestk[rt][rg];
                idx[v0 + v] = k;
                atomicAdd(&crep[k], 1.0f);
                enc[(v0 + v) * (size_t)K_CODES + k] = 1.0f;
            }
    }
}

// ---------------------------------------------------------------------------
// dw segment-sum into 16 replica buffers (replica = v & 15).
// Block = 256 vectors; wave handles 64; lane = d. Contiguous 256B row atomics.
// ---------------------------------------------------------------------------
__global__ __launch_bounds__(256) void dw_scatter_kernel(
    const float* __restrict__ inputs,
    const int* __restrict__ idx,
    float* __restrict__ dwrep)
{
    __shared__ int sIdx[256];
    const int t = threadIdx.x;
    const size_t vbase = (size_t)blockIdx.x * 256;
    sIdx[t] = idx[vbase + t];
    __syncthreads();
    const int w = t >> 6, lane = t & 63;
    const int v0 = w * 64;
#pragma unroll 4
    for (int j = 0; j < 64; ++j) {
        const int v = v0 + j;
        const int k = sIdx[v];
        const float xv = inputs[(vbase + v) * DIM + lane];
        atomicAdd(&dwrep[((v & (NREP - 1)) << 15) + (k << 6) + lane], xv);
    }
}

// ---------------------------------------------------------------------------
// emaA: counts replica-reduce + EMA cluster size + Laplace + perplexity.
// ---------------------------------------------------------------------------
__global__ __launch_bounds__(512) void emaA_kernel(
    const float* __restrict__ counts_rep,
    const float* __restrict__ ema_cs,
    float* __restrict__ csbuf,
    float* __restrict__ perp_out)
{
    __shared__ float red[K_CODES];
    const int k = threadIdx.x;
    float cnt = 0.f;
#pragma unroll
    for (int r = 0; r < NREP; ++r) cnt += counts_rep[r * K_CODES + k];
    float cs = ema_cs[k] * 0.99f + 0.01f * cnt;

    red[k] = cs;
    __syncthreads();
    for (int s = K_CODES / 2; s > 0; s >>= 1) {
        if (k < s) red[k] += red[k + s];
        __syncthreads();
    }
    const float n = red[0];
    __syncthreads();

    csbuf[k] = (cs + 1e-5f) / (n + (float)K_CODES * 1e-5f) * n;

    const float p = cnt * (1.0f / (float)N_VEC);
    red[k] = p * logf(p + 1e-10f);
    __syncthreads();
    for (int s = K_CODES / 2; s > 0; s >>= 1) {
        if (k < s) red[k] += red[k + s];
        __syncthreads();
    }
    if (k == 0) perp_out[0] = expf(-red[0]);
}

// ---------------------------------------------------------------------------
// emaB: dw replica-reduce + codebook update. 32768 (k,d) threads.
// ---------------------------------------------------------------------------
__global__ __launch_bounds__(256) void emaB_kernel(
    const float* __restrict__ dwrep,
    const float* __restrict__ ema_w,
    const float* __restrict__ csbuf,
    float* __restrict__ new_emb)
{
    const int t = blockIdx.x * 256 + threadIdx.x;   // 0..32767 = k*64+d
    const int k = t >> 6;
    float dwv = 0.f;
#pragma unroll
    for (int r = 0; r < NREP; ++r) dwv += dwrep[(r << 15) + t];
    const float v = ema_w[t] * 0.99f + 0.01f * dwv;
    new_emb[t] = v / csbuf[k];
}

// ---------------------------------------------------------------------------
// quantize: gather + straight-through + NHWC->NCHW + commitment loss.
// ---------------------------------------------------------------------------
__global__ __launch_bounds__(256) void quantize_kernel(
    const float* __restrict__ inputs,
    const int* __restrict__ idx,
    const float* __restrict__ new_emb,
    float* __restrict__ out_q,
    float* __restrict__ loss_accum)
{
    __shared__ int sIdx[64];
    __shared__ float tile[DIM][65];
    __shared__ float wsum[4];

    const int bh = blockIdx.x;
    const int b = bh >> 6, h = bh & 63;
    const int t = threadIdx.x;

    if (t < 64) sIdx[t] = idx[bh * 64 + t];
    __syncthreads();

    const float* inRow = inputs + (size_t)bh * 64 * DIM;
    const int d = t & 63;
    const int wg = t >> 6;
    float lsum = 0.f;
#pragma unroll
    for (int p = 0; p < 16; ++p) {
        const int w = wg * 16 + p;
        const float xv = inRow[w * DIM + d];
        const float qv = new_emb[sIdx[w] * DIM + d];
        const float diff = qv - xv;
        tile[d][w] = xv + diff;
        lsum = fmaf(diff, diff, lsum);
    }
    __syncthreads();

    const int w2 = t & 63;
    const int dg = t >> 6;
#pragma unroll
    for (int p = 0; p < 16; ++p) {
        const int d2 = dg * 16 + p;
        out_q[(((size_t)b * DIM + d2) * 64 + h) * 64 + w2] = tile[d2][w2];
    }

    for (int off = 32; off > 0; off >>= 1) lsum += __shfl_down(lsum, off);
    if ((t & 63) == 0) wsum[t >> 6] = lsum;
    __syncthreads();
    if (t == 0) atomicAdd(loss_accum, (wsum[0] + wsum[1]) + (wsum[2] + wsum[3]));
}

__global__ void finalize_kernel(const float* __restrict__ loss_accum,
                                float* __restrict__ out_loss)
{
    out_loss[0] = 0.25f * (loss_accum[0] / 8388608.0f);
}

// ---------------------------------------------------------------------------
extern "C" void kernel_launch(void* const* d_in, const int* in_sizes, int n_in,
                              void* d_out, int out_size, void* d_ws, size_t ws_size,
                              hipStream_t stream)
{
    const float* inputs = (const float*)d_in[0];
    const float* emb_w  = (const float*)d_in[1];
    const float* ema_cs = (const float*)d_in[2];
    const float* ema_w  = (const float*)d_in[3];
    float* out = (float*)d_out;
    float* ws  = (float*)d_ws;

    // ws layout (f32 offsets), ~888 KB total:
    int*   idxbuf  = (int*)ws;              // [0, 131072)
    float* crep    = ws + 131072;           // [131072, 139264)  16x512
    float* lossac  = ws + 139264;           // [139264]
    float* csbuf   = ws + 139265;           // [139265, 139777)
    float* eebuf   = ws + 139777;           // [139777, 140289)
    float* nemb    = ws + 140289;           // [140289, 173057)
    bfrag* epack   = (bfrag*)(ws + 173060); // 192 KB, 16B-aligned

    // dw replicas (2 MB) live in the not-yet-written quantized region of
    // d_out (out+16, 64B-aligned); overwritten by quantize_kernel afterwards.
    float* dwrep = out + 16;

    hipMemsetAsync(crep, 0, (NREP * K_CODES + 1) * sizeof(float), stream); // crep+lossac
    hipMemsetAsync(dwrep, 0, NREP * K_CODES * DIM * sizeof(float), stream);

    ee_kernel<<<K_CODES / 64, 64, 0, stream>>>(emb_w, eebuf);
    epack_kernel<<<16, 256, 0, stream>>>(emb_w, epack);

    enc_zero_kernel<<<2048, 256, 0, stream>>>(out + ENC_OFF);

    argmin_mfma_kernel<<<N_VEC / 128, 256, 0, stream>>>(
        inputs, epack, eebuf, idxbuf, crep, out + ENC_OFF);

    dw_scatter_kernel<<<N_VEC / 256, 256, 0, stream>>>(inputs, idxbuf, dwrep);

    emaA_kernel<<<1, K_CODES, 0, stream>>>(crep, ema_cs, csbuf, out + PERP_OFF);
    emaB_kernel<<<K_CODES * DIM / 256, 256, 0, stream>>>(dwrep, ema_w, csbuf, nemb);

    quantize_kernel<<<32 * 64, 256, 0, stream>>>(
        inputs, idxbuf, nemb, out + Q_OFF, lossac);

    finalize_kernel<<<1, 1, 0, stream>>>(lossac, out);
}